// Round 1
// baseline (305.691 us; speedup 1.0000x reference)
//
#include <hip/hip_runtime.h>
#include <hip/hip_bf16.h>
#include <cstdint>
#include <cstddef>

// ---------------------------------------------------------------------------
// MixedRationalQuadraticCouplingTransform:
//   net_in = [cos(ic), sin(ic), ir, context]  (96+64 = 160, padded to 192)
//   h1 = relu(net_in @ W1 + b1); h2 = relu(h1 @ W2 + b2); params = h2 @ W3 + b3
//   RQ-spline per tc (circular, 15 params) / tr (16 params) feature.
// Staged: prep_weights, prep_input, 3x bf16 MFMA GEMM, spline kernel.
// ---------------------------------------------------------------------------

#define BM 128
#define BN 128
#define BK 64

typedef float  f32x4 __attribute__((ext_vector_type(4)));
typedef short  s16x8 __attribute__((ext_vector_type(8)));

__device__ __forceinline__ void mfma_bf16_16x16x32(f32x4& acc, s16x8 a, s16x8 b) {
    // D = A*B + C, C==D (accumulate). asm avoids builtin operand-type ambiguity.
    asm volatile("v_mfma_f32_16x16x32_bf16 %0, %1, %2, %0"
                 : "+v"(acc) : "v"(a), "v"(b));
}

__device__ __forceinline__ void gload_lds16(const void* g, void* lds) {
    __builtin_amdgcn_global_load_lds((const __attribute__((address_space(1))) void*)g,
                                     (__attribute__((address_space(3))) void*)lds,
                                     16, 0, 0);
}

__device__ __forceinline__ float bf2f(short s) {
    union { unsigned u; float f; } v;
    v.u = ((unsigned)(unsigned short)s) << 16;
    return v.f;
}

// ---------------- prep kernels ----------------

__global__ void prep_input_kernel(const float* __restrict__ inputs,
                                  const float* __restrict__ context,
                                  __hip_bfloat16* __restrict__ netin)
{
    const int n = blockIdx.x;
    const int c = threadIdx.x;  // 0..191
    float v;
    if (c < 32)       v = cosf(inputs[(size_t)n * 128 + c]);
    else if (c < 64)  v = sinf(inputs[(size_t)n * 128 + (c - 32)]);
    else if (c < 96)  v = inputs[(size_t)n * 128 + c];          // ir = cols 64..95
    else if (c < 160) v = context[(size_t)n * 64 + (c - 96)];
    else              v = 0.f;                                   // K pad 160..191
    netin[(size_t)n * 192 + c] = __float2bfloat16(v);
}

__global__ void prep_weights_kernel(const float* __restrict__ W1,
                                    const float* __restrict__ W2,
                                    const float* __restrict__ W3,
                                    const float* __restrict__ b3,
                                    __hip_bfloat16* __restrict__ W1T,
                                    __hip_bfloat16* __restrict__ W2T,
                                    __hip_bfloat16* __restrict__ W3T,
                                    float* __restrict__ b3p)
{
    const int T1 = 512 * 192, T2 = 512 * 512, T3 = 1024 * 512;
    const int total = T1 + T2 + T3 + 1024;
    for (int t = blockIdx.x * blockDim.x + threadIdx.x; t < total;
         t += gridDim.x * blockDim.x) {
        if (t < T1) {
            int nn = t / 192, k = t % 192;
            float v = (k < 160) ? W1[(size_t)k * 512 + nn] : 0.f;
            W1T[t] = __float2bfloat16(v);
        } else if (t < T1 + T2) {
            int u = t - T1;
            int nn = u / 512, k = u % 512;
            W2T[u] = __float2bfloat16(W2[(size_t)k * 512 + nn]);
        } else if (t < T1 + T2 + T3) {
            int u = t - T1 - T2;
            int nn = u / 512, k = u % 512;
            float v = (nn < 992) ? W3[(size_t)k * 992 + nn] : 0.f;
            W3T[u] = __float2bfloat16(v);
        } else {
            int u = t - T1 - T2 - T3;
            b3p[u] = (u < 992) ? b3[u] : 0.f;
        }
    }
}

// ---------------- GEMM: C[M,Nc] = A[M,K] @ BT[Nc,K]^T + bias, opt relu ----

template<bool RELU>
__global__ __launch_bounds__(256)
void gemm_bt_kernel(const __hip_bfloat16* __restrict__ A,
                    const __hip_bfloat16* __restrict__ BT,
                    const float* __restrict__ bias,
                    __hip_bfloat16* __restrict__ C,
                    int M, int Nc, int K)
{
    __shared__ __align__(16) short Ald[BM * BK];
    __shared__ __align__(16) short Bld[BN * BK];

    const int tid  = threadIdx.x;
    const int wid  = tid >> 6;
    const int lane = tid & 63;
    const int row0 = blockIdx.y * BM;
    const int col0 = blockIdx.x * BN;
    const int wr   = (wid >> 1) * 64;   // wave row offset in tile
    const int wc   = (wid & 1) * 64;    // wave col offset in tile

    f32x4 acc[4][4] = {};

    const int srow  = lane >> 3;        // 8 rows per 1KB chunk
    const int scolb = (lane & 7) * 16;  // byte offset within 128B row

    const char* Abase = (const char*)A  + (size_t)row0 * K * 2;
    const char* Bbase = (const char*)BT + (size_t)col0 * K * 2;

    const int fr = lane & 15;           // fragment row/col
    const int fq = lane >> 4;           // k-group / acc row group

    const int nk = K / BK;
    for (int kt = 0; kt < nk; ++kt) {
        __syncthreads();
#pragma unroll
        for (int i = 0; i < 4; ++i) {
            const int chunk = i * 4 + wid;        // 0..15, 1KB each
            const int r = chunk * 8 + srow;
            gload_lds16(Abase + ((size_t)r * K + (size_t)kt * BK) * 2 + scolb,
                        (char*)Ald + chunk * 1024);
            gload_lds16(Bbase + ((size_t)r * K + (size_t)kt * BK) * 2 + scolb,
                        (char*)Bld + chunk * 1024);
        }
        __syncthreads();
#pragma unroll
        for (int kk = 0; kk < 2; ++kk) {
            s16x8 af[4], bfv[4];
#pragma unroll
            for (int m = 0; m < 4; ++m)
                af[m] = *(const s16x8*)&Ald[(wr + m * 16 + fr) * BK + kk * 32 + fq * 8];
#pragma unroll
            for (int n = 0; n < 4; ++n)
                bfv[n] = *(const s16x8*)&Bld[(wc + n * 16 + fr) * BK + kk * 32 + fq * 8];
#pragma unroll
            for (int m = 0; m < 4; ++m)
#pragma unroll
                for (int n = 0; n < 4; ++n)
                    mfma_bf16_16x16x32(acc[m][n], af[m], bfv[n]);
        }
    }

    // epilogue: bias (+relu) + bf16 store. C/D layout: col=lane&15, row=(lane>>4)*4+r
#pragma unroll
    for (int n = 0; n < 4; ++n) {
        const int col = col0 + wc + n * 16 + fr;
        const float bv = bias[col];
#pragma unroll
        for (int m = 0; m < 4; ++m) {
            const int rbase = row0 + wr + m * 16 + fq * 4;
#pragma unroll
            for (int r = 0; r < 4; ++r) {
                float v = acc[m][n][r] + bv;
                if (RELU) v = fmaxf(v, 0.f);
                C[(size_t)(rbase + r) * Nc + col] = __float2bfloat16(v);
            }
        }
    }
}

// ---------------- spline kernel: 1 wave per row, 1 lane per feature -------

__global__ __launch_bounds__(256)
void spline_kernel(const float* __restrict__ inputs,
                   const __hip_bfloat16* __restrict__ params,  // [N][1024] bf16
                   float* __restrict__ out, int Nrows)
{
    __shared__ __align__(16) short plds[4][1024];
    const int wid  = threadIdx.x >> 6;
    const int lane = threadIdx.x & 63;
    const int row  = blockIdx.x * 4 + wid;

    // stage params row (992 bf16 = 124 x 16B) into LDS, coalesced
    const short* prow = (const short*)params + (size_t)row * 1024;
    for (int c = lane; c < 124; c += 64)
        ((int4*)&plds[wid][0])[c] = ((const int4*)prow)[c];
    __syncthreads();

    const bool circ = lane < 32;
    const int  j    = circ ? lane : lane - 32;
    const float PI_F  = 3.14159265358979323846f;
    const float left  = circ ? -PI_F : -5.0f;
    const float right = -left;
    const float SCALE = 0.04419417382415922f;  // 1/sqrt(512)

    const short* pp = &plds[wid][circ ? j * 15 : 480 + j * 16];

    float uw[5], uh[5], ud[6];
#pragma unroll
    for (int i = 0; i < 5; ++i) uw[i] = bf2f(pp[i]) * SCALE;
#pragma unroll
    for (int i = 0; i < 5; ++i) uh[i] = bf2f(pp[5 + i]) * SCALE;
    if (circ) {
#pragma unroll
        for (int i = 0; i < 5; ++i) ud[i] = bf2f(pp[10 + i]);
        ud[5] = ud[0];  // circular wrap
    } else {
#pragma unroll
        for (int i = 0; i < 6; ++i) ud[i] = bf2f(pp[10 + i]);
    }

    const int xcol = circ ? (32 + j) : (96 + j);
    const float x  = inputs[(size_t)row * 128 + xcol];

    // widths softmax -> cumulative knots cw[0..5]
    float mx = uw[0];
#pragma unroll
    for (int i = 1; i < 5; ++i) mx = fmaxf(mx, uw[i]);
    float e[5], s = 0.f;
#pragma unroll
    for (int i = 0; i < 5; ++i) { e[i] = __expf(uw[i] - mx); s += e[i]; }
    const float inv_s = 1.f / s;
    float cw[6];
    cw[0] = left;
    {
        float accw = 0.f;
#pragma unroll
        for (int i = 0; i < 5; ++i) {
            float wn = 0.001f + 0.995f * (e[i] * inv_s);
            accw += wn;
            cw[i + 1] = left + (right - left) * accw;
        }
    }
    cw[5] = right;

    // heights softmax -> ch[0..5]
    float mh = uh[0];
#pragma unroll
    for (int i = 1; i < 5; ++i) mh = fmaxf(mh, uh[i]);
    float eh[5], sh = 0.f;
#pragma unroll
    for (int i = 0; i < 5; ++i) { eh[i] = __expf(uh[i] - mh); sh += eh[i]; }
    const float inv_sh = 1.f / sh;
    float ch[6];
    ch[0] = left;
    {
        float acch = 0.f;
#pragma unroll
        for (int i = 0; i < 5; ++i) {
            float hn = 0.001f + 0.995f * (eh[i] * inv_sh);
            acch += hn;
            ch[i + 1] = left + (right - left) * acch;
        }
    }
    ch[5] = right;

    // derivatives = MIN_D + softplus(ud)
    float d[6];
#pragma unroll
    for (int i = 0; i < 6; ++i) {
        float u  = ud[i];
        float sp = fmaxf(u, 0.f) + log1pf(__expf(-fabsf(u)));
        d[i] = 0.001f + sp;
    }

    const float xc = fminf(fmaxf(x, left), right);
    int b = 0;
#pragma unroll
    for (int i = 1; i <= 5; ++i) b += (xc >= cw[i]) ? 1 : 0;
    b = (b > 4) ? 4 : b;

    // select bin values with unrolled cndmask chain (no runtime array indexing)
    float l_cw = cw[0], r_cw = cw[1], l_ch = ch[0], r_ch = ch[1], dk = d[0], dk1 = d[1];
#pragma unroll
    for (int i = 1; i < 5; ++i) {
        if (b == i) {
            l_cw = cw[i]; r_cw = cw[i + 1];
            l_ch = ch[i]; r_ch = ch[i + 1];
            dk   = d[i];  dk1  = d[i + 1];
        }
    }

    const float iw  = r_cw - l_cw;
    const float ih  = r_ch - l_ch;
    const float del = ih / iw;
    const float th  = (xc - l_cw) / iw;
    const float omt = 1.f - th;
    const float num = ih * (del * th * th + dk * th * omt);
    const float den = del + (dk + dk1 - 2.f * del) * th * omt;
    float y = l_ch + num / den;
    const float dnum = del * del * (dk1 * th * th + 2.f * del * th * omt + dk * omt * omt);
    float lad = __logf(dnum) - 2.f * __logf(den);

    if (!circ) {
        const bool inside = (x >= -5.0f) && (x <= 5.0f);
        if (!inside) { y = x; lad = 0.f; }
    }

    // identity copies + transformed outputs
    const int ccol = circ ? j : 64 + j;
    out[(size_t)row * 128 + ccol] = inputs[(size_t)row * 128 + ccol];
    out[(size_t)row * 128 + xcol] = y;

    // logabsdet = wave-sum of lad
    float t = lad;
#pragma unroll
    for (int o = 32; o > 0; o >>= 1) t += __shfl_xor(t, o, 64);
    if (lane == 0) out[(size_t)Nrows * 128 + row] = t;
}

// ---------------- launcher -------------------------------------------------

extern "C" void kernel_launch(void* const* d_in, const int* in_sizes, int n_in,
                              void* d_out, int out_size, void* d_ws, size_t ws_size,
                              hipStream_t stream)
{
    const float* inputs  = (const float*)d_in[0];
    const float* context = (const float*)d_in[1];
    const float* W1 = (const float*)d_in[2];
    const float* b1 = (const float*)d_in[3];
    const float* W2 = (const float*)d_in[4];
    const float* b2 = (const float*)d_in[5];
    const float* W3 = (const float*)d_in[6];
    const float* b3 = (const float*)d_in[7];
    float* out = (float*)d_out;

    const int Nrows = in_sizes[0] / 128;  // 65536

    char* ws = (char*)d_ws;
    const size_t szh    = (size_t)Nrows * 512 * 2;   // h1/h2 bf16
    const size_t sznet  = (size_t)Nrows * 192 * 2;   // net_in bf16 (padded)
    const size_t szpar  = (size_t)Nrows * 1024 * 2;  // params bf16 (padded)
    const size_t off_h2     = 0;
    const size_t off_netin  = szh;
    const size_t off_h1     = szh + sznet;
    const size_t off_params = szh;                   // overlaps dead netin+h1
    const size_t off_w1t    = szh + szpar;
    const size_t off_w2t    = off_w1t + (size_t)512 * 192 * 2;
    const size_t off_w3t    = off_w2t + (size_t)512 * 512 * 2;
    const size_t off_b3p    = off_w3t + (size_t)1024 * 512 * 2;

    __hip_bfloat16* netin  = (__hip_bfloat16*)(ws + off_netin);
    __hip_bfloat16* h1     = (__hip_bfloat16*)(ws + off_h1);
    __hip_bfloat16* h2     = (__hip_bfloat16*)(ws + off_h2);
    __hip_bfloat16* params = (__hip_bfloat16*)(ws + off_params);
    __hip_bfloat16* W1T    = (__hip_bfloat16*)(ws + off_w1t);
    __hip_bfloat16* W2T    = (__hip_bfloat16*)(ws + off_w2t);
    __hip_bfloat16* W3T    = (__hip_bfloat16*)(ws + off_w3t);
    float*          b3p    = (float*)(ws + off_b3p);

    prep_weights_kernel<<<2048, 256, 0, stream>>>(W1, W2, W3, b3, W1T, W2T, W3T, b3p);
    prep_input_kernel<<<Nrows, 192, 0, stream>>>(inputs, context, netin);

    gemm_bt_kernel<true ><<<dim3(4, Nrows / 128), 256, 0, stream>>>(
        netin, W1T, b1, h1, Nrows, 512, 192);
    gemm_bt_kernel<true ><<<dim3(4, Nrows / 128), 256, 0, stream>>>(
        h1, W2T, b2, h2, Nrows, 512, 512);
    gemm_bt_kernel<false><<<dim3(8, Nrows / 128), 256, 0, stream>>>(
        h2, W3T, b3p, params, Nrows, 1024, 512);

    spline_kernel<<<Nrows / 4, 256, 0, stream>>>(inputs, params, out, Nrows);
}